// Round 8
// baseline (209.308 us; speedup 1.0000x reference)
//
#include <hip/hip_runtime.h>

// Problem constants (match reference)
#define V_ 100000
#define D_ 256
#define M_ 4096
#define C_ 4096
#define L_ 32
#define ROWS_MEMS (M_ + 1)          // 4097 rows in mems_enc (mems + xs_emb)
#define NTASK (1 + M_ + 1 + C_)     // 8194 encode row-tasks
#define NBLK 1025                   // 4100 waves; wave g does rows g and g+4100
#define HALF (NBLK * 4)             // 4100
#define NV4 ((V_ * D_) / 4)         // 6.4M float4s in lt

__device__ __forceinline__ float wave_allreduce_sum(float v) {
    #pragma unroll
    for (int off = 32; off >= 1; off >>= 1) v += __shfl_xor(v, off, 64);
    return v;
}

// butterfly within each 32-lane half: every lane gets its half's sum
__device__ __forceinline__ float half_allreduce_sum(float v) {
    #pragma unroll
    for (int off = 16; off >= 1; off >>= 1) v += __shfl_xor(v, off, 64);
    return v;
}

__device__ __forceinline__ unsigned short f2bf_rne(float f) {
    unsigned int u = __float_as_uint(f);
    u += 0x7FFFu + ((u >> 16) & 1u);     // round-to-nearest-even
    return (unsigned short)(u >> 16);
}
__device__ __forceinline__ float bf2f(unsigned short b) {
    return __uint_as_float((unsigned int)b << 16);
}

// ---------------------------------------------------------------------------
// K0: stream-convert lt (fp32, 102 MB) -> bf16 table (51 MB) in ws.
// Pure BW-bound: float4 in, ushort4 out, one element group per thread.
// ---------------------------------------------------------------------------
__global__ __launch_bounds__(256) void convert_lt(
    const float4* __restrict__ lt4, ushort4* __restrict__ bt4)
{
    const int i = blockIdx.x * 256 + threadIdx.x;
    if (i >= NV4) return;
    const float4 v = lt4[i];
    ushort4 o;
    o.x = f2bf_rne(v.x); o.y = f2bf_rne(v.y);
    o.z = f2bf_rne(v.z); o.w = f2bf_rne(v.w);
    bt4[i] = o;
}

// ---------------------------------------------------------------------------
// K1: fused encode + attention + weighted accumulation, gathering from the
// bf16 table: each row-gather is 512 B (8 cache lines) instead of 1 KB (16),
// testing the per-CU outstanding-line ceiling theory. 2 rows per wave:
// row-A tokens in lanes 0..31, row-B tokens in lanes 32..63.
//   Row A (g in 0..4099): rows 0..4096 fuse exp(cos) + LDS/global accumulate
//   (cos in [-1,1] -> exp without max-subtraction is safe); 4097=ys,
//   4098/4099 = cands 0/1 -> straight to out_ys.
//   Row B (g+4100): always a cands row -> straight to out_ys.
// ---------------------------------------------------------------------------
__global__ __launch_bounds__(256) void encode_fused(
    const int* __restrict__ xs, const int* __restrict__ mems,
    const int* __restrict__ ys, const int* __restrict__ cands,
    const unsigned short* __restrict__ bt,   // bf16 table [V_, D_]
    const float* __restrict__ freqs,
    float* __restrict__ lhs_raw,   // [256], zeroed: sum_i e_i * row_i
    float* __restrict__ gsum,      // [1],  zeroed: sum_i e_i
    float* __restrict__ out_ys)    // d_out second half: [4097, 256]
{
    __shared__ float s_xf[D_];     // xs embedding fragment
    __shared__ float s_lred[D_];   // block partial of sum e*row
    __shared__ float s_an2, s_ered;

    const int wave = threadIdx.x >> 6;
    const int lane = threadIdx.x & 63;
    const int d0 = lane * 4;               // 64 lanes x 4 dims = 256
    const int g = blockIdx.x * 4 + wave;   // 0..4099

    s_lred[threadIdx.x] = 0.f;
    if (threadIdx.x == 0) s_ered = 0.f;

    // wave 0: xs fragment once per block (32 L2-hot rows)
    if (wave == 0) {
        int txs = 0; float wxs = 0.f;
        if (lane < L_) { txs = xs[lane]; wxs = freqs[txs]; }
        const float sx2 = wave_allreduce_sum(wxs * wxs);
        const float wnx = wxs / sqrtf(sx2);
        float4 xf = make_float4(0.f, 0.f, 0.f, 0.f);
        #pragma unroll
        for (int l = 0; l < L_; ++l) {
            const int t = __shfl(txs, l, 64);
            const float wl = __shfl(wnx, l, 64);
            const ushort4 b = *reinterpret_cast<const ushort4*>(bt + (size_t)t * D_ + d0);
            xf.x += wl * bf2f(b.x); xf.y += wl * bf2f(b.y);
            xf.z += wl * bf2f(b.z); xf.w += wl * bf2f(b.w);
        }
        *reinterpret_cast<float4*>(&s_xf[d0]) = xf;
        const float an2 = wave_allreduce_sum(xf.x*xf.x + xf.y*xf.y + xf.z*xf.z + xf.w*xf.w);
        if (lane == 0) s_an2 = an2;
    }
    __syncthreads();

    // ---- resolve row A (rt in 0..4099)
    const int rtA = g;
    const int* tpA; float* dstA = nullptr; int aiA = -1;
    if (rtA == 0) {
        tpA = xs; aiA = M_;
    } else if (rtA <= M_) {
        tpA = mems + (size_t)(rtA - 1) * L_; aiA = rtA - 1;
    } else if (rtA == M_ + 1) {
        tpA = ys; dstA = out_ys;
    } else {
        const int c = rtA - (M_ + 2);
        tpA = cands + (size_t)c * L_;
        dstA = out_ys + (size_t)(c + 1) * D_;
    }

    // ---- resolve row B (rt = g+4100; valid ones are all cands rows)
    const int rtB = g + HALF;
    const bool hasB = (rtB < NTASK);
    const int cB = hasB ? (rtB - (M_ + 2)) : 0;
    const int* tpB = cands + (size_t)cB * L_;
    float* dstB = out_ys + (size_t)(cB + 1) * D_;

    // tokens: lanes 0..31 = row A, lanes 32..63 = row B
    const int tok = (lane < 32) ? tpA[lane] : tpB[lane - 32];
    const float w = freqs[tok];
    const float s2 = half_allreduce_sum(w * w);   // per-half norm
    const float wn = w / sqrtf(s2);               // freqs > 0 -> s2 > 0

    // ---- gather loop: 64 independent 512B row-reads per wave (8 lines each)
    float4 accA = make_float4(0.f, 0.f, 0.f, 0.f);
    float4 accB = make_float4(0.f, 0.f, 0.f, 0.f);
    #pragma unroll
    for (int l = 0; l < L_; ++l) {
        const int   ta = __shfl(tok, l, 64);
        const int   tb = __shfl(tok, 32 + l, 64);
        const float wa = __shfl(wn, l, 64);
        const float wb = __shfl(wn, 32 + l, 64);
        const ushort4 ba = *reinterpret_cast<const ushort4*>(bt + (size_t)ta * D_ + d0);
        const ushort4 bb = *reinterpret_cast<const ushort4*>(bt + (size_t)tb * D_ + d0);
        accA.x += wa * bf2f(ba.x); accA.y += wa * bf2f(ba.y);
        accA.z += wa * bf2f(ba.z); accA.w += wa * bf2f(ba.w);
        accB.x += wb * bf2f(bb.x); accB.y += wb * bf2f(bb.y);
        accB.z += wb * bf2f(bb.z); accB.w += wb * bf2f(bb.w);
    }

    // ---- row A epilogue: attention fuse or direct store
    if (aiA >= 0) {
        const float4 xf = *reinterpret_cast<const float4*>(&s_xf[d0]);
        const float d = wave_allreduce_sum(accA.x*xf.x + accA.y*xf.y + accA.z*xf.z + accA.w*xf.w);
        const float q = wave_allreduce_sum(accA.x*accA.x + accA.y*accA.y + accA.z*accA.z + accA.w*accA.w);
        const float an = fmaxf(sqrtf(s_an2), 1e-8f);
        const float bn = fmaxf(sqrtf(q),  1e-8f);
        const float e = expf(d / (an * bn));     // same value on all lanes
        atomicAdd(&s_lred[d0 + 0], e * accA.x);  // LDS atomics: 4-wave combine
        atomicAdd(&s_lred[d0 + 1], e * accA.y);
        atomicAdd(&s_lred[d0 + 2], e * accA.z);
        atomicAdd(&s_lred[d0 + 3], e * accA.w);
        if (lane == 0) atomicAdd(&s_ered, e);
    } else {
        *reinterpret_cast<float4*>(dstA + d0) = accA;
    }
    // ---- row B epilogue: always a cands row
    if (hasB) *reinterpret_cast<float4*>(dstB + d0) = accB;

    // ---- block combine -> global accumulators
    __syncthreads();
    atomicAdd(&lhs_raw[threadIdx.x], s_lred[threadIdx.x]);
    if (threadIdx.x == 0) atomicAdd(gsum, s_ered);
}

// ---------------------------------------------------------------------------
// K2: normalize lhs by the softmax denominator and tile into out_xs rows.
// ---------------------------------------------------------------------------
__global__ __launch_bounds__(256) void finalize_tile(
    const float* __restrict__ lhs_raw, const float* __restrict__ gsum,
    float* __restrict__ out_xs)
{
    const float val = lhs_raw[threadIdx.x] / gsum[0];
    for (int r = blockIdx.x; r < ROWS_MEMS; r += gridDim.x)
        out_xs[(size_t)r * D_ + threadIdx.x] = val;
}

extern "C" void kernel_launch(void* const* d_in, const int* in_sizes, int n_in,
                              void* d_out, int out_size, void* d_ws, size_t ws_size,
                              hipStream_t stream) {
    const int*   xs    = (const int*)d_in[0];
    const int*   mems  = (const int*)d_in[1];
    const int*   ys    = (const int*)d_in[2];
    const int*   cands = (const int*)d_in[3];
    const float* lt    = (const float*)d_in[4];
    const float* freqs = (const float*)d_in[5];

    float* out    = (float*)d_out;
    float* out_xs = out;                                   // [4097, 256]
    float* out_ys = out + (size_t)ROWS_MEMS * D_;          // [4097, 256]

    // ws layout: bf16 table [V_*D_ ushort = 51.2 MB] | lhs_raw[256] | gsum[1]
    unsigned short* bt = (unsigned short*)d_ws;
    float* lhs_raw = (float*)(bt + (size_t)V_ * D_);
    float* gsum    = lhs_raw + D_;

    hipMemsetAsync(lhs_raw, 0, (D_ + 1) * sizeof(float), stream);

    convert_lt<<<(NV4 + 255) / 256, 256, 0, stream>>>(
        (const float4*)lt, (ushort4*)bt);
    encode_fused<<<NBLK, 256, 0, stream>>>(xs, mems, ys, cands, bt, freqs,
                                           lhs_raw, gsum, out_ys);
    finalize_tile<<<1024, 256, 0, stream>>>(lhs_raw, gsum, out_xs);
}